// Round 7
// baseline (165.890 us; speedup 1.0000x reference)
//
#include <hip/hip_runtime.h>
#include <stdint.h>

#pragma clang fp contract(off)

typedef unsigned long long u64;
typedef unsigned int u32;

#define NF 8192
#define NP 2048
#define TPB 256
#define PPT 2          // points per thread
#define FPB 32         // faces per block chunk (32 -> 1024 blocks, 4 waves/SIMD)
#define NBLK ((NP / (TPB * PPT)) * (NF / FPB))   // 4 * 256 = 1024
#define PACKED_OFF (NF * 4 * sizeof(float4))     // 512 KiB of face data first
#define CTR_OFF (PACKED_OFF + NP * sizeof(u64))  // counter after packed

__device__ __forceinline__ float safef(float x) {
  // reference: where(|x| > 1e-12, x, 1e-12)
  return fabsf(x) > 1e-12f ? x : 1e-12f;
}

// BLAS-style K=3 dot: fma(z,bz, fma(y,by, x*bx)) — matches np/XLA sgemm rounding
__device__ __forceinline__ float dot3_fma(float px, float py, float pz,
                                          float bx, float by, float bz) {
  return __fmaf_rn(pz, bz, __fmaf_rn(py, by, px * bx));
}

// ---------------------------------------------------------------------------
// Kernel 1: per-face precompute + packed/counter init (fused, kills memset).
// fd[4*f+0..3] = {a,aa} {ab,abab} {ac,acac} {abac,a_ab,a_ac,0}
// ---------------------------------------------------------------------------
__global__ __launch_bounds__(TPB) void face_pre(const u32* __restrict__ fw,
                                                const float* __restrict__ verts,
                                                float4* __restrict__ fd,
                                                u64* __restrict__ packed,
                                                u32* __restrict__ counter) {
  const int f = blockIdx.x * blockDim.x + threadIdx.x;
  if (f < NP) packed[f] = ~0ull;   // +inf pattern for packed min
  if (f == 0) *counter = 0u;

  bool odd_zero = true;
#pragma unroll
  for (int k = 0; k < 16; ++k) odd_zero = odd_zero && (fw[2 * k + 1] == 0u);

  if (f >= NF) return;

  int ia, ib, ic;
  if (odd_zero) {  // int64 faces: low words at even offsets
    ia = (int)fw[6 * f + 0];
    ib = (int)fw[6 * f + 2];
    ic = (int)fw[6 * f + 4];
  } else {         // int32 faces
    ia = (int)fw[3 * f + 0];
    ib = (int)fw[3 * f + 1];
    ic = (int)fw[3 * f + 2];
  }
  const float ax = verts[3 * ia + 0], ay = verts[3 * ia + 1], az = verts[3 * ia + 2];
  const float bx = verts[3 * ib + 0], by = verts[3 * ib + 1], bz = verts[3 * ib + 2];
  const float cx = verts[3 * ic + 0], cy = verts[3 * ic + 1], cz = verts[3 * ic + 2];

  const float abx = bx - ax, aby = by - ay, abz = bz - az;
  const float acx = cx - ax, acy = cy - ay, acz = cz - az;
  const float abab = (abx * abx + aby * aby) + abz * abz;
  const float acac = (acx * acx + acy * acy) + acz * acz;
  const float abac = (abx * acx + aby * acy) + abz * acz;
  const float aa   = (ax * ax + ay * ay) + az * az;
  const float a_ab = (ax * abx + ay * aby) + az * abz;
  const float a_ac = (ax * acx + ay * acy) + az * acz;

  fd[4 * f + 0] = make_float4(ax, ay, az, aa);
  fd[4 * f + 1] = make_float4(abx, aby, abz, abab);
  fd[4 * f + 2] = make_float4(acx, acy, acz, acac);
  fd[4 * f + 3] = make_float4(abac, a_ab, a_ac, 0.0f);
}

// ---------------------------------------------------------------------------
// Per-pair squared distance: point-side dots via FMA chains (BLAS/XLA-like),
// all elementwise ops plain IEEE fp32 L2R, no contraction. Verified absmax 0.
// ---------------------------------------------------------------------------
__device__ __forceinline__ float tri_sq(float px, float py, float pz, float pp,
                                        float4 c0, float4 c1, float4 c2, float4 c3) {
  const float aa = c0.w;
  const float abab = c1.w, acac = c2.w;
  const float abac = c3.x, a_ab = c3.y, a_ac = c3.z;

  const float d1 = dot3_fma(px, py, pz, c1.x, c1.y, c1.z) - a_ab;
  const float d2 = dot3_fma(px, py, pz, c2.x, c2.y, c2.z) - a_ac;
  const float d3 = d1 - abab;
  const float d4 = d2 - abac;
  const float d5 = d1 - abac;
  const float d6 = d2 - acac;
  const float pa = dot3_fma(px, py, pz, c0.x, c0.y, c0.z);
  const float apap = (pp - 2.0f * pa) + aa;

  const float va = d3 * d6 - d5 * d4;
  const float vb = d5 * d2 - d1 * d6;
  const float vc = d1 * d4 - d3 * d2;

  const float t_ab = d1 / safef(d1 - d3);
  const float t_ac = d2 / safef(d2 - d6);
  const float nbc = d4 - d3;
  const float mbc = d5 - d6;
  const float t_bc = nbc / safef(nbc + mbc);

  const float denom = safef((va + vb) + vc);
  float v = vb / denom;
  float w = vc / denom;

  const bool cBC = (va <= 0.0f) && (nbc >= 0.0f) && (mbc >= 0.0f);
  v = cBC ? (1.0f - t_bc) : v;
  w = cBC ? t_bc : w;
  const bool cAC = (vb <= 0.0f) && (d2 >= 0.0f) && (d6 <= 0.0f);
  v = cAC ? 0.0f : v;
  w = cAC ? t_ac : w;
  const bool cC = (d6 >= 0.0f) && (d5 <= d6);
  v = cC ? 0.0f : v;
  w = cC ? 1.0f : w;
  const bool cAB = (vc <= 0.0f) && (d1 >= 0.0f) && (d3 <= 0.0f);
  v = cAB ? t_ab : v;
  w = cAB ? 0.0f : w;
  const bool cB = (d3 >= 0.0f) && (d4 <= d3);
  v = cB ? 1.0f : v;
  w = cB ? 0.0f : w;
  const bool cA = (d1 <= 0.0f) && (d2 <= 0.0f);
  v = cA ? 0.0f : v;
  w = cA ? 0.0f : w;

  const float sq = ((((apap - (2.0f * v) * d1) - (2.0f * w) * d2) + (v * v) * abab)
                    + ((2.0f * v) * w) * abac) + (w * w) * acac;
  return fmaxf(sq, 0.0f);
}

// ---------------------------------------------------------------------------
// Kernel 2: pair sweep + fused last-block finalize.
// Each thread: 2 points vs FPB faces; per-point min packed (f32bits<<32)|f
// merged via atomicMin (ties -> lowest face index, like jnp.argmin).
// Last block (atomic counter) unpacks -> dist, assoc, loss.
// ---------------------------------------------------------------------------
__global__ __launch_bounds__(TPB) void pair_kernel(const float4* __restrict__ fd,
                                                   const float* __restrict__ pts,
                                                   u64* __restrict__ packed,
                                                   u32* __restrict__ counter,
                                                   float* __restrict__ out) {
  const int t = threadIdx.x;
  const int p0 = blockIdx.x * (TPB * PPT) + t;
  const int p1 = p0 + TPB;
  const int fbase = blockIdx.y * FPB;

  const float p0x = pts[3 * p0 + 0], p0y = pts[3 * p0 + 1], p0z = pts[3 * p0 + 2];
  const float p1x = pts[3 * p1 + 0], p1y = pts[3 * p1 + 1], p1z = pts[3 * p1 + 2];
  // pp mimics np elementwise sum(points*points): plain mul/add L2R
  const float pp0 = (p0x * p0x + p0y * p0y) + p0z * p0z;
  const float pp1 = (p1x * p1x + p1y * p1y) + p1z * p1z;

  u64 b0 = ~0ull, b1 = ~0ull;
  for (int j = 0; j < FPB; ++j) {
    const int f = fbase + j;
    const float4 c0 = fd[4 * f + 0];
    const float4 c1 = fd[4 * f + 1];
    const float4 c2 = fd[4 * f + 2];
    const float4 c3 = fd[4 * f + 3];
    const float s0 = tri_sq(p0x, p0y, p0z, pp0, c0, c1, c2, c3);
    const float s1 = tri_sq(p1x, p1y, p1z, pp1, c0, c1, c2, c3);
    const u64 k0 = ((u64)__float_as_uint(s0) << 32) | (u32)f;
    const u64 k1 = ((u64)__float_as_uint(s1) << 32) | (u32)f;
    b0 = (k0 < b0) ? k0 : b0;
    b1 = (k1 < b1) ? k1 : b1;
  }
  atomicMin(&packed[p0], b0);
  atomicMin(&packed[p1], b1);

  // ---- last-block finalize ----
  __shared__ int is_last;
  __shared__ float sdata[TPB];
  __threadfence();  // make our atomicMin results globally visible before count
  if (t == 0) {
    const u32 old = atomicAdd(counter, 1u);
    is_last = (old == (u32)(NBLK - 1)) ? 1 : 0;
  }
  __syncthreads();
  if (!is_last) return;

  // All other blocks have fenced + counted: packed is final. Read via no-op
  // atomicMin (returns old value) — device-scope read, no stale-L1 risk.
  float acc = 0.0f;
  for (int i = t; i < NP; i += TPB) {
    const u64 k = atomicMin(&packed[i], ~0ull);
    const float d = __uint_as_float((u32)(k >> 32));
    const u32 idx = (u32)k;
    out[1 + i] = d;
    out[1 + NP + i] = (float)idx;
    acc += d;
  }
  sdata[t] = acc;
  __syncthreads();
  for (int s = TPB / 2; s > 0; s >>= 1) {
    if (t < s) sdata[t] += sdata[t + s];
    __syncthreads();
  }
  if (t == 0) out[0] = sdata[0] / (float)NP;
}

extern "C" void kernel_launch(void* const* d_in, const int* in_sizes, int n_in,
                              void* d_out, int out_size, void* d_ws, size_t ws_size,
                              hipStream_t stream) {
  const float* verts = (const float*)d_in[0];
  const u32* facesw = (const u32*)d_in[1];
  const float* points = (const float*)d_in[2];
  float* out = (float*)d_out;

  float4* fd = (float4*)d_ws;
  u64* packed = (u64*)((char*)d_ws + PACKED_OFF);
  u32* counter = (u32*)((char*)d_ws + CTR_OFF);

  face_pre<<<NF / TPB, TPB, 0, stream>>>(facesw, verts, fd, packed, counter);
  pair_kernel<<<dim3(NP / (TPB * PPT), NF / FPB), TPB, 0, stream>>>(fd, points, packed,
                                                                    counter, out);
}

// Round 15
// 132.712 us; speedup vs baseline: 1.2500x; 1.2500x over previous
//
#include <hip/hip_runtime.h>
#include <stdint.h>

#pragma clang fp contract(off)

typedef unsigned long long u64;
typedef unsigned int u32;

#define NF 8192
#define NP 2048
#define TPB 256
#define FPB 64         // faces per block chunk; PPT=1 -> grid 8 x 128 = 1024 blocks
#define PACKED_OFF (NF * 4 * sizeof(float4))     // 512 KiB of face data first

__device__ __forceinline__ float safef(float x) {
  // reference: where(|x| > 1e-12, x, 1e-12)
  return fabsf(x) > 1e-12f ? x : 1e-12f;
}

// BLAS-style K=3 dot: fma(z,bz, fma(y,by, x*bx)) — matches np/XLA sgemm rounding
__device__ __forceinline__ float dot3_fma(float px, float py, float pz,
                                          float bx, float by, float bz) {
  return __fmaf_rn(pz, bz, __fmaf_rn(py, by, px * bx));
}

// ---------------------------------------------------------------------------
// Kernel 1: per-face precompute + packed init (kills the memset dispatch).
// fd[4*f+0..3] = {a,aa} {ab,abab} {ac,acac} {abac,a_ab,a_ac,0}
// ---------------------------------------------------------------------------
__global__ __launch_bounds__(TPB) void face_pre(const u32* __restrict__ fw,
                                                const float* __restrict__ verts,
                                                float4* __restrict__ fd,
                                                u64* __restrict__ packed) {
  const int f = blockIdx.x * blockDim.x + threadIdx.x;
  if (f < NP) packed[f] = ~0ull;   // +inf pattern for packed min

  bool odd_zero = true;
#pragma unroll
  for (int k = 0; k < 16; ++k) odd_zero = odd_zero && (fw[2 * k + 1] == 0u);

  if (f >= NF) return;

  int ia, ib, ic;
  if (odd_zero) {  // int64 faces: low words at even offsets
    ia = (int)fw[6 * f + 0];
    ib = (int)fw[6 * f + 2];
    ic = (int)fw[6 * f + 4];
  } else {         // int32 faces
    ia = (int)fw[3 * f + 0];
    ib = (int)fw[3 * f + 1];
    ic = (int)fw[3 * f + 2];
  }
  const float ax = verts[3 * ia + 0], ay = verts[3 * ia + 1], az = verts[3 * ia + 2];
  const float bx = verts[3 * ib + 0], by = verts[3 * ib + 1], bz = verts[3 * ib + 2];
  const float cx = verts[3 * ic + 0], cy = verts[3 * ic + 1], cz = verts[3 * ic + 2];

  const float abx = bx - ax, aby = by - ay, abz = bz - az;
  const float acx = cx - ax, acy = cy - ay, acz = cz - az;
  const float abab = (abx * abx + aby * aby) + abz * abz;
  const float acac = (acx * acx + acy * acy) + acz * acz;
  const float abac = (abx * acx + aby * acy) + abz * acz;
  const float aa   = (ax * ax + ay * ay) + az * az;
  const float a_ab = (ax * abx + ay * aby) + az * abz;
  const float a_ac = (ax * acx + ay * acy) + az * acz;

  fd[4 * f + 0] = make_float4(ax, ay, az, aa);
  fd[4 * f + 1] = make_float4(abx, aby, abz, abab);
  fd[4 * f + 2] = make_float4(acx, acy, acz, acac);
  fd[4 * f + 3] = make_float4(abac, a_ab, a_ac, 0.0f);
}

// ---------------------------------------------------------------------------
// Per-pair squared distance: point-side dots via FMA chains (BLAS/XLA-like),
// all elementwise ops plain IEEE fp32 L2R, no contraction. Verified absmax 0.
// ---------------------------------------------------------------------------
__device__ __forceinline__ float tri_sq(float px, float py, float pz, float pp,
                                        float4 c0, float4 c1, float4 c2, float4 c3) {
  const float aa = c0.w;
  const float abab = c1.w, acac = c2.w;
  const float abac = c3.x, a_ab = c3.y, a_ac = c3.z;

  const float d1 = dot3_fma(px, py, pz, c1.x, c1.y, c1.z) - a_ab;
  const float d2 = dot3_fma(px, py, pz, c2.x, c2.y, c2.z) - a_ac;
  const float d3 = d1 - abab;
  const float d4 = d2 - abac;
  const float d5 = d1 - abac;
  const float d6 = d2 - acac;
  const float pa = dot3_fma(px, py, pz, c0.x, c0.y, c0.z);
  const float apap = (pp - 2.0f * pa) + aa;

  const float va = d3 * d6 - d5 * d4;
  const float vb = d5 * d2 - d1 * d6;
  const float vc = d1 * d4 - d3 * d2;

  const float t_ab = d1 / safef(d1 - d3);
  const float t_ac = d2 / safef(d2 - d6);
  const float nbc = d4 - d3;
  const float mbc = d5 - d6;
  const float t_bc = nbc / safef(nbc + mbc);

  const float denom = safef((va + vb) + vc);
  float v = vb / denom;
  float w = vc / denom;

  const bool cBC = (va <= 0.0f) && (nbc >= 0.0f) && (mbc >= 0.0f);
  v = cBC ? (1.0f - t_bc) : v;
  w = cBC ? t_bc : w;
  const bool cAC = (vb <= 0.0f) && (d2 >= 0.0f) && (d6 <= 0.0f);
  v = cAC ? 0.0f : v;
  w = cAC ? t_ac : w;
  const bool cC = (d6 >= 0.0f) && (d5 <= d6);
  v = cC ? 0.0f : v;
  w = cC ? 1.0f : w;
  const bool cAB = (vc <= 0.0f) && (d1 >= 0.0f) && (d3 <= 0.0f);
  v = cAB ? t_ab : v;
  w = cAB ? 0.0f : w;
  const bool cB = (d3 >= 0.0f) && (d4 <= d3);
  v = cB ? 1.0f : v;
  w = cB ? 0.0f : w;
  const bool cA = (d1 <= 0.0f) && (d2 <= 0.0f);
  v = cA ? 0.0f : v;
  w = cA ? 0.0f : w;

  const float sq = ((((apap - (2.0f * v) * d1) - (2.0f * w) * d2) + (v * v) * abab)
                    + ((2.0f * v) * w) * abac) + (w * w) * acac;
  return fmaxf(sq, 0.0f);
}

// ---------------------------------------------------------------------------
// Kernel 2: grid = (point-groups 8, face-chunks 128) = 1024 blocks.
// Each thread: ONE point vs 64 faces (PPT=1: max TLP, atomics unchanged).
// Face loads are wave-uniform -> SMEM pipe (s_load), not VALU.
// Per-point min packed (f32bits<<32)|f merged via atomicMin
// (ties -> lowest face index, like jnp.argmin).
// ---------------------------------------------------------------------------
__global__ __launch_bounds__(TPB) void pair_kernel(const float4* __restrict__ fd,
                                                   const float* __restrict__ pts,
                                                   u64* __restrict__ packed) {
  const int t = threadIdx.x;
  const int p = blockIdx.x * TPB + t;
  const int fbase = blockIdx.y * FPB;

  const float px = pts[3 * p + 0], py = pts[3 * p + 1], pz = pts[3 * p + 2];
  // pp mimics np elementwise sum(points*points): plain mul/add L2R
  const float pp = (px * px + py * py) + pz * pz;

  u64 best = ~0ull;
  for (int j = 0; j < FPB; ++j) {
    const int f = fbase + j;
    const float4 c0 = fd[4 * f + 0];
    const float4 c1 = fd[4 * f + 1];
    const float4 c2 = fd[4 * f + 2];
    const float4 c3 = fd[4 * f + 3];
    const float s = tri_sq(px, py, pz, pp, c0, c1, c2, c3);
    const u64 k = ((u64)__float_as_uint(s) << 32) | (u32)f;
    best = (k < best) ? k : best;
  }
  atomicMin(&packed[p], best);
}

// ---------------------------------------------------------------------------
// Kernel 3: unpack -> dist, assoc (as float), loss = sum(dist)/NP.
// ---------------------------------------------------------------------------
__global__ __launch_bounds__(TPB) void finalize(const u64* __restrict__ packed,
                                                float* __restrict__ out) {
  __shared__ float sdata[TPB];
  const int t = threadIdx.x;
  float acc = 0.0f;
  for (int i = t; i < NP; i += TPB) {
    const u64 k = packed[i];
    const float d = __uint_as_float((u32)(k >> 32));
    const u32 idx = (u32)k;
    out[1 + i] = d;
    out[1 + NP + i] = (float)idx;
    acc += d;
  }
  sdata[t] = acc;
  __syncthreads();
  for (int s = TPB / 2; s > 0; s >>= 1) {
    if (t < s) sdata[t] += sdata[t + s];
    __syncthreads();
  }
  if (t == 0) out[0] = sdata[0] / (float)NP;
}

extern "C" void kernel_launch(void* const* d_in, const int* in_sizes, int n_in,
                              void* d_out, int out_size, void* d_ws, size_t ws_size,
                              hipStream_t stream) {
  const float* verts = (const float*)d_in[0];
  const u32* facesw = (const u32*)d_in[1];
  const float* points = (const float*)d_in[2];
  float* out = (float*)d_out;

  float4* fd = (float4*)d_ws;
  u64* packed = (u64*)((char*)d_ws + PACKED_OFF);

  face_pre<<<NF / TPB, TPB, 0, stream>>>(facesw, verts, fd, packed);
  pair_kernel<<<dim3(NP / TPB, NF / FPB), TPB, 0, stream>>>(fd, points, packed);
  finalize<<<1, TPB, 0, stream>>>(packed, out);
}

// Round 16
// 116.440 us; speedup vs baseline: 1.4247x; 1.1397x over previous
//
#include <hip/hip_runtime.h>
#include <stdint.h>

#pragma clang fp contract(off)

typedef unsigned long long u64;
typedef unsigned int u32;

#define NF 8192
#define NP 2048
#define TPB 256
#define FPB 64         // faces per block chunk; grid 8 x 128 = 1024 blocks
#define PACKED_OFF (NF * 4 * sizeof(float4))     // 512 KiB of face data first

__device__ __forceinline__ float safef(float x) {
  // reference: where(|x| > 1e-12, x, 1e-12)
  return fabsf(x) > 1e-12f ? x : 1e-12f;
}

// BLAS-style K=3 dot: fma(z,bz, fma(y,by, x*bx)) — matches np/XLA sgemm rounding
__device__ __forceinline__ float dot3_fma(float px, float py, float pz,
                                          float bx, float by, float bz) {
  return __fmaf_rn(pz, bz, __fmaf_rn(py, by, px * bx));
}

// ---------------------------------------------------------------------------
// Kernel 1: per-face precompute + packed init (kills the memset dispatch).
// fd[4*f+0..3] = {a,aa} {ab,abab} {ac,acac} {abac,a_ab,a_ac,0}
// ---------------------------------------------------------------------------
__global__ __launch_bounds__(TPB) void face_pre(const u32* __restrict__ fw,
                                                const float* __restrict__ verts,
                                                float4* __restrict__ fd,
                                                u64* __restrict__ packed) {
  const int f = blockIdx.x * blockDim.x + threadIdx.x;
  if (f < NP) packed[f] = ~0ull;   // +inf pattern for packed min

  bool odd_zero = true;
#pragma unroll
  for (int k = 0; k < 16; ++k) odd_zero = odd_zero && (fw[2 * k + 1] == 0u);

  if (f >= NF) return;

  int ia, ib, ic;
  if (odd_zero) {  // int64 faces: low words at even offsets
    ia = (int)fw[6 * f + 0];
    ib = (int)fw[6 * f + 2];
    ic = (int)fw[6 * f + 4];
  } else {         // int32 faces
    ia = (int)fw[3 * f + 0];
    ib = (int)fw[3 * f + 1];
    ic = (int)fw[3 * f + 2];
  }
  const float ax = verts[3 * ia + 0], ay = verts[3 * ia + 1], az = verts[3 * ia + 2];
  const float bx = verts[3 * ib + 0], by = verts[3 * ib + 1], bz = verts[3 * ib + 2];
  const float cx = verts[3 * ic + 0], cy = verts[3 * ic + 1], cz = verts[3 * ic + 2];

  const float abx = bx - ax, aby = by - ay, abz = bz - az;
  const float acx = cx - ax, acy = cy - ay, acz = cz - az;
  const float abab = (abx * abx + aby * aby) + abz * abz;
  const float acac = (acx * acx + acy * acy) + acz * acz;
  const float abac = (abx * acx + aby * acy) + abz * acz;
  const float aa   = (ax * ax + ay * ay) + az * az;
  const float a_ab = (ax * abx + ay * aby) + az * abz;
  const float a_ac = (ax * acx + ay * acy) + az * acz;

  fd[4 * f + 0] = make_float4(ax, ay, az, aa);
  fd[4 * f + 1] = make_float4(abx, aby, abz, abab);
  fd[4 * f + 2] = make_float4(acx, acy, acz, acac);
  fd[4 * f + 3] = make_float4(abac, a_ab, a_ac, 0.0f);
}

// ---------------------------------------------------------------------------
// Per-pair squared distance. Point-side dots via FMA chains (verified absmax
// 0 vs np). NEW: only 2 IEEE divides instead of 5 — the region is resolved
// FIRST (priority cA>cB>cAB>cC>cAC>cBC>interior = reference's overwrite
// order), then per-lane cndmask selects the divide operands. The selected
// quotient is bit-identical to the reference's for the governing region.
// ---------------------------------------------------------------------------
__device__ __forceinline__ float tri_sq(float px, float py, float pz, float pp,
                                        float4 c0, float4 c1, float4 c2, float4 c3) {
  const float aa = c0.w;
  const float abab = c1.w, acac = c2.w;
  const float abac = c3.x, a_ab = c3.y, a_ac = c3.z;

  const float d1 = dot3_fma(px, py, pz, c1.x, c1.y, c1.z) - a_ab;
  const float d2 = dot3_fma(px, py, pz, c2.x, c2.y, c2.z) - a_ac;
  const float d3 = d1 - abab;
  const float d4 = d2 - abac;
  const float d5 = d1 - abac;
  const float d6 = d2 - acac;
  const float pa = dot3_fma(px, py, pz, c0.x, c0.y, c0.z);
  const float apap = (pp - 2.0f * pa) + aa;

  const float va = d3 * d6 - d5 * d4;
  const float vb = d5 * d2 - d1 * d6;
  const float vc = d1 * d4 - d3 * d2;

  const float nbc = d4 - d3;
  const float mbc = d5 - d6;
  const float s1r = d1 - d3;          // t_ab denominator (raw)
  const float s2r = d2 - d6;          // t_ac denominator (raw)
  const float s3r = nbc + mbc;        // t_bc denominator (raw)
  const float denr = (va + vb) + vc;  // interior denominator (raw)

  const bool cBC = (va <= 0.0f) && (nbc >= 0.0f) && (mbc >= 0.0f);
  const bool cAC = (vb <= 0.0f) && (d2 >= 0.0f) && (d6 <= 0.0f);
  const bool cC  = (d6 >= 0.0f) && (d5 <= d6);
  const bool cAB = (vc <= 0.0f) && (d1 >= 0.0f) && (d3 <= 0.0f);
  const bool cB  = (d3 >= 0.0f) && (d4 <= d3);
  const bool cA  = (d1 <= 0.0f) && (d2 <= 0.0f);

  // effective (priority-resolved) masks for divide-operand selection
  const bool hB  = cA || cB;
  const bool hAB = hB || cAB;
  const bool hC  = hAB || cC;
  const bool hAC = hC || cAC;
  const bool eAB = cAB && !hB;
  const bool eAC = cAC && !hC;
  const bool eBC = cBC && !hAC;

  // q1 serves: interior v (vb/denom), AB's t_ab (d1/s1), BC's t_bc (nbc/s3)
  const float n1 = eBC ? nbc : (eAB ? d1 : vb);
  const float e1 = eBC ? s3r : (eAB ? s1r : denr);
  // q2 serves: interior w (vc/denom), AC's t_ac (d2/s2)
  const float n2 = eAC ? d2 : vc;
  const float e2 = eAC ? s2r : denr;
  const float q1 = n1 / safef(e1);
  const float q2 = n2 / safef(e2);

  // priority chain == reference's sequential overwrites (last-true wins)
  const float v = cA ? 0.0f
                : cB ? 1.0f
                : cAB ? q1
                : cC ? 0.0f
                : cAC ? 0.0f
                : cBC ? (1.0f - q1)
                : q1;
  const float w = cA ? 0.0f
                : cB ? 0.0f
                : cAB ? 0.0f
                : cC ? 1.0f
                : cAC ? q2
                : cBC ? q1
                : q2;

  const float sq = ((((apap - (2.0f * v) * d1) - (2.0f * w) * d2) + (v * v) * abab)
                    + ((2.0f * v) * w) * abac) + (w * w) * acac;
  return fmaxf(sq, 0.0f);
}

// ---------------------------------------------------------------------------
// Kernel 2: grid = (point-groups 8, face-chunks 128) = 1024 blocks.
// Each thread: ONE point vs 64 faces. Face loads wave-uniform (SMEM pipe).
// Per-point min packed (f32bits<<32)|f merged via atomicMin
// (ties -> lowest face index, like jnp.argmin).
// ---------------------------------------------------------------------------
__global__ __launch_bounds__(TPB) void pair_kernel(const float4* __restrict__ fd,
                                                   const float* __restrict__ pts,
                                                   u64* __restrict__ packed) {
  const int t = threadIdx.x;
  const int p = blockIdx.x * TPB + t;
  const int fbase = blockIdx.y * FPB;

  const float px = pts[3 * p + 0], py = pts[3 * p + 1], pz = pts[3 * p + 2];
  // pp mimics np elementwise sum(points*points): plain mul/add L2R
  const float pp = (px * px + py * py) + pz * pz;

  u64 best = ~0ull;
#pragma unroll 2
  for (int j = 0; j < FPB; ++j) {
    const int f = fbase + j;
    const float4 c0 = fd[4 * f + 0];
    const float4 c1 = fd[4 * f + 1];
    const float4 c2 = fd[4 * f + 2];
    const float4 c3 = fd[4 * f + 3];
    const float s = tri_sq(px, py, pz, pp, c0, c1, c2, c3);
    const u64 k = ((u64)__float_as_uint(s) << 32) | (u32)f;
    best = (k < best) ? k : best;
  }
  atomicMin(&packed[p], best);
}

// ---------------------------------------------------------------------------
// Kernel 3: unpack -> dist, assoc (as float), loss = sum(dist)/NP.
// ---------------------------------------------------------------------------
__global__ __launch_bounds__(TPB) void finalize(const u64* __restrict__ packed,
                                                float* __restrict__ out) {
  __shared__ float sdata[TPB];
  const int t = threadIdx.x;
  float acc = 0.0f;
  for (int i = t; i < NP; i += TPB) {
    const u64 k = packed[i];
    const float d = __uint_as_float((u32)(k >> 32));
    const u32 idx = (u32)k;
    out[1 + i] = d;
    out[1 + NP + i] = (float)idx;
    acc += d;
  }
  sdata[t] = acc;
  __syncthreads();
  for (int s = TPB / 2; s > 0; s >>= 1) {
    if (t < s) sdata[t] += sdata[t + s];
    __syncthreads();
  }
  if (t == 0) out[0] = sdata[0] / (float)NP;
}

extern "C" void kernel_launch(void* const* d_in, const int* in_sizes, int n_in,
                              void* d_out, int out_size, void* d_ws, size_t ws_size,
                              hipStream_t stream) {
  const float* verts = (const float*)d_in[0];
  const u32* facesw = (const u32*)d_in[1];
  const float* points = (const float*)d_in[2];
  float* out = (float*)d_out;

  float4* fd = (float4*)d_ws;
  u64* packed = (u64*)((char*)d_ws + PACKED_OFF);

  face_pre<<<NF / TPB, TPB, 0, stream>>>(facesw, verts, fd, packed);
  pair_kernel<<<dim3(NP / TPB, NF / FPB), TPB, 0, stream>>>(fd, points, packed);
  finalize<<<1, TPB, 0, stream>>>(packed, out);
}

// Round 18
// 111.213 us; speedup vs baseline: 1.4916x; 1.0470x over previous
//
#include <hip/hip_runtime.h>
#include <stdint.h>

#pragma clang fp contract(off)

typedef unsigned long long u64;
typedef unsigned int u32;

#define NF 8192
#define NP 2048
#define TPB 256
#define FPB 32         // faces per block chunk; grid 8 x 256 = 2048 blocks = 32 waves/CU
#define PACKED_OFF (NF * 4 * sizeof(float4))     // 512 KiB of face data first

__device__ __forceinline__ float safef(float x) {
  // reference: where(|x| > 1e-12, x, 1e-12)
  return fabsf(x) > 1e-12f ? x : 1e-12f;
}

// BLAS-style K=3 dot: fma(z,bz, fma(y,by, x*bx)) — matches np/XLA sgemm rounding
__device__ __forceinline__ float dot3_fma(float px, float py, float pz,
                                          float bx, float by, float bz) {
  return __fmaf_rn(pz, bz, __fmaf_rn(py, by, px * bx));
}

// ---------------------------------------------------------------------------
// Kernel 1: per-face precompute + packed init (kills the memset dispatch).
// fd[4*f+0..3] = {a,aa} {ab,abab} {ac,acac} {abac,a_ab,a_ac,0}
// ---------------------------------------------------------------------------
__global__ __launch_bounds__(TPB) void face_pre(const u32* __restrict__ fw,
                                                const float* __restrict__ verts,
                                                float4* __restrict__ fd,
                                                u64* __restrict__ packed) {
  const int f = blockIdx.x * blockDim.x + threadIdx.x;
  if (f < NP) packed[f] = ~0ull;   // +inf pattern for packed min

  bool odd_zero = true;
#pragma unroll
  for (int k = 0; k < 16; ++k) odd_zero = odd_zero && (fw[2 * k + 1] == 0u);

  if (f >= NF) return;

  int ia, ib, ic;
  if (odd_zero) {  // int64 faces: low words at even offsets
    ia = (int)fw[6 * f + 0];
    ib = (int)fw[6 * f + 2];
    ic = (int)fw[6 * f + 4];
  } else {         // int32 faces
    ia = (int)fw[3 * f + 0];
    ib = (int)fw[3 * f + 1];
    ic = (int)fw[3 * f + 2];
  }
  const float ax = verts[3 * ia + 0], ay = verts[3 * ia + 1], az = verts[3 * ia + 2];
  const float bx = verts[3 * ib + 0], by = verts[3 * ib + 1], bz = verts[3 * ib + 2];
  const float cx = verts[3 * ic + 0], cy = verts[3 * ic + 1], cz = verts[3 * ic + 2];

  const float abx = bx - ax, aby = by - ay, abz = bz - az;
  const float acx = cx - ax, acy = cy - ay, acz = cz - az;
  const float abab = (abx * abx + aby * aby) + abz * abz;
  const float acac = (acx * acx + acy * acy) + acz * acz;
  const float abac = (abx * acx + aby * acy) + abz * acz;
  const float aa   = (ax * ax + ay * ay) + az * az;
  const float a_ab = (ax * abx + ay * aby) + az * abz;
  const float a_ac = (ax * acx + ay * acy) + az * acz;

  fd[4 * f + 0] = make_float4(ax, ay, az, aa);
  fd[4 * f + 1] = make_float4(abx, aby, abz, abab);
  fd[4 * f + 2] = make_float4(acx, acy, acz, acac);
  fd[4 * f + 3] = make_float4(abac, a_ab, a_ac, 0.0f);
}

// ---------------------------------------------------------------------------
// Per-pair squared distance. Point-side dots via FMA chains (verified absmax
// 0 vs np). Only 2 IEEE divides — region resolved first (priority
// cA>cB>cAB>cC>cAC>cBC>interior = reference's overwrite order), then
// cndmask-selected divide operands. Bit-identical to reference per region.
// ---------------------------------------------------------------------------
__device__ __forceinline__ float tri_sq(float px, float py, float pz, float pp,
                                        float4 c0, float4 c1, float4 c2, float4 c3) {
  const float aa = c0.w;
  const float abab = c1.w, acac = c2.w;
  const float abac = c3.x, a_ab = c3.y, a_ac = c3.z;

  const float d1 = dot3_fma(px, py, pz, c1.x, c1.y, c1.z) - a_ab;
  const float d2 = dot3_fma(px, py, pz, c2.x, c2.y, c2.z) - a_ac;
  const float d3 = d1 - abab;
  const float d4 = d2 - abac;
  const float d5 = d1 - abac;
  const float d6 = d2 - acac;
  const float pa = dot3_fma(px, py, pz, c0.x, c0.y, c0.z);
  const float apap = (pp - 2.0f * pa) + aa;

  const float va = d3 * d6 - d5 * d4;
  const float vb = d5 * d2 - d1 * d6;
  const float vc = d1 * d4 - d3 * d2;

  const float nbc = d4 - d3;
  const float mbc = d5 - d6;
  const float s1r = d1 - d3;          // t_ab denominator (raw)
  const float s2r = d2 - d6;          // t_ac denominator (raw)
  const float s3r = nbc + mbc;        // t_bc denominator (raw)
  const float denr = (va + vb) + vc;  // interior denominator (raw)

  const bool cBC = (va <= 0.0f) && (nbc >= 0.0f) && (mbc >= 0.0f);
  const bool cAC = (vb <= 0.0f) && (d2 >= 0.0f) && (d6 <= 0.0f);
  const bool cC  = (d6 >= 0.0f) && (d5 <= d6);
  const bool cAB = (vc <= 0.0f) && (d1 >= 0.0f) && (d3 <= 0.0f);
  const bool cB  = (d3 >= 0.0f) && (d4 <= d3);
  const bool cA  = (d1 <= 0.0f) && (d2 <= 0.0f);

  // effective (priority-resolved) masks for divide-operand selection
  const bool hB  = cA || cB;
  const bool hAB = hB || cAB;
  const bool hC  = hAB || cC;
  const bool hAC = hC || cAC;
  const bool eAB = cAB && !hB;
  const bool eAC = cAC && !hC;
  const bool eBC = cBC && !hAC;

  // q1 serves: interior v (vb/denom), AB's t_ab (d1/s1), BC's t_bc (nbc/s3)
  const float n1 = eBC ? nbc : (eAB ? d1 : vb);
  const float e1 = eBC ? s3r : (eAB ? s1r : denr);
  // q2 serves: interior w (vc/denom), AC's t_ac (d2/s2)
  const float n2 = eAC ? d2 : vc;
  const float e2 = eAC ? s2r : denr;
  const float q1 = n1 / safef(e1);
  const float q2 = n2 / safef(e2);

  // priority chain == reference's sequential overwrites (last-true wins)
  const float v = cA ? 0.0f
                : cB ? 1.0f
                : cAB ? q1
                : cC ? 0.0f
                : cAC ? 0.0f
                : cBC ? (1.0f - q1)
                : q1;
  const float w = cA ? 0.0f
                : cB ? 0.0f
                : cAB ? 0.0f
                : cC ? 1.0f
                : cAC ? q2
                : cBC ? q1
                : q2;

  const float sq = ((((apap - (2.0f * v) * d1) - (2.0f * w) * d2) + (v * v) * abab)
                    + ((2.0f * v) * w) * abac) + (w * w) * acac;
  return fmaxf(sq, 0.0f);
}

// ---------------------------------------------------------------------------
// Kernel 2: grid = (point-groups 8, face-chunks 256) = 2048 blocks
// (= 8 blocks/CU = 32 waves/CU, the occupancy cap). Each thread: ONE point
// vs 32 faces. Face loads wave-uniform (SMEM pipe). Per-point min packed
// (f32bits<<32)|f merged via atomicMin (ties -> lowest face index).
// ---------------------------------------------------------------------------
__global__ __launch_bounds__(TPB) void pair_kernel(const float4* __restrict__ fd,
                                                   const float* __restrict__ pts,
                                                   u64* __restrict__ packed) {
  const int t = threadIdx.x;
  const int p = blockIdx.x * TPB + t;
  const int fbase = blockIdx.y * FPB;

  const float px = pts[3 * p + 0], py = pts[3 * p + 1], pz = pts[3 * p + 2];
  // pp mimics np elementwise sum(points*points): plain mul/add L2R
  const float pp = (px * px + py * py) + pz * pz;

  u64 best = ~0ull;
#pragma unroll 2
  for (int j = 0; j < FPB; ++j) {
    const int f = fbase + j;
    const float4 c0 = fd[4 * f + 0];
    const float4 c1 = fd[4 * f + 1];
    const float4 c2 = fd[4 * f + 2];
    const float4 c3 = fd[4 * f + 3];
    const float s = tri_sq(px, py, pz, pp, c0, c1, c2, c3);
    const u64 k = ((u64)__float_as_uint(s) << 32) | (u32)f;
    best = (k < best) ? k : best;
  }
  atomicMin(&packed[p], best);
}

// ---------------------------------------------------------------------------
// Kernel 3: unpack -> dist, assoc (as float), loss = sum(dist)/NP.
// ---------------------------------------------------------------------------
__global__ __launch_bounds__(TPB) void finalize(const u64* __restrict__ packed,
                                                float* __restrict__ out) {
  __shared__ float sdata[TPB];
  const int t = threadIdx.x;
  float acc = 0.0f;
  for (int i = t; i < NP; i += TPB) {
    const u64 k = packed[i];
    const float d = __uint_as_float((u32)(k >> 32));
    const u32 idx = (u32)k;
    out[1 + i] = d;
    out[1 + NP + i] = (float)idx;
    acc += d;
  }
  sdata[t] = acc;
  __syncthreads();
  for (int s = TPB / 2; s > 0; s >>= 1) {
    if (t < s) sdata[t] += sdata[t + s];
    __syncthreads();
  }
  if (t == 0) out[0] = sdata[0] / (float)NP;
}

extern "C" void kernel_launch(void* const* d_in, const int* in_sizes, int n_in,
                              void* d_out, int out_size, void* d_ws, size_t ws_size,
                              hipStream_t stream) {
  const float* verts = (const float*)d_in[0];
  const u32* facesw = (const u32*)d_in[1];
  const float* points = (const float*)d_in[2];
  float* out = (float*)d_out;

  float4* fd = (float4*)d_ws;
  u64* packed = (u64*)((char*)d_ws + PACKED_OFF);

  face_pre<<<NF / TPB, TPB, 0, stream>>>(facesw, verts, fd, packed);
  pair_kernel<<<dim3(NP / TPB, NF / FPB), TPB, 0, stream>>>(fd, points, packed);
  finalize<<<1, TPB, 0, stream>>>(packed, out);
}